// Round 14
// baseline (40.011 us; speedup 1.0000x reference)
//
#include <hip/hip_runtime.h>
#include <math.h>

#define BB 4
#define CC 64
#define NN 4096
#define IND 8
#define HF 32
#define QBLK 32
#define THREADS 512
#define WAVES 8
#define MBLK 32
#define MCHUNK (NN/WAVES)    // 512 m's per wave
#define NBLK (MCHUNK/MBLK)   // 16 blocks

typedef __attribute__((ext_vector_type(8))) short bf16x8;
typedef __attribute__((ext_vector_type(4))) float f32x4;

static __device__ __forceinline__ unsigned short f2bf(float x) {
    unsigned int u = __float_as_uint(x);
    u = (u + 0x7FFFu + ((u >> 16) & 1u)) >> 16;   // RNE
    return (unsigned short)u;
}
static __device__ __forceinline__ float bf2f(unsigned short h) {
    return __uint_as_float(((unsigned int)h) << 16);
}
static __device__ __forceinline__ unsigned int pk2(float lo, float hi) {
    return (unsigned int)f2bf(lo) | ((unsigned int)f2bf(hi) << 16);
}
static __device__ __forceinline__ float ex2(float x) {
    return __builtin_amdgcn_exp2f(x);   // v_exp_f32 (2^x)
}

// m -> k-slot coding shared by P (in-register) and V (blocked layout):
// k(m5) = (m5&3) | ((m5>>4)&1)<<2 | ((m5>>2)&3)<<3   (bijective on 0..31)
//
// V layout: vblk[b][mb][hg][c15][ks] u16 (2 KB per mb) -> contiguous wave-load.
// x layout fix (R14): x reads in proj were 64 loads/thread at 16 KB stride
// (bits [13:8] shared -> one L2 channel slice; measured 1.3 TB/s). Transpose
// once to xT[b][n][c] f32 -> proj reads 256 B contiguous per thread.

// Kernel 0: x [B][C][N] -> xT [B][N][C]. No LDS: reads coalesced (lanes =
// consecutive n, contiguous 256 B), writes 32 B/thread at 256-B lane stride
// (channel bits vary with n -> spread). 512 WGs x 256 threads.
__global__ __launch_bounds__(256) void xpose_kernel(
    const float* __restrict__ x, float* __restrict__ xT)
{
    int bx = blockIdx.x;
    int b  = bx >> 7;
    int cg = (bx >> 4) & 7;            // c-chunk of 8
    int nt = bx & 15;
    int n  = nt * 256 + threadIdx.x;
    const float* xp = x + ((size_t)b * CC + cg * 8) * NN + n;
    float v[8];
    #pragma unroll
    for (int i = 0; i < 8; i++) v[i] = xp[(size_t)i * NN];
    float4* dst = (float4*)(xT + ((size_t)(b * NN + n)) * CC + cg * 8);
    dst[0] = make_float4(v[0], v[1], v[2], v[3]);
    dst[1] = make_float4(v[4], v[5], v[6], v[7]);
}

// Kernel 1: 1x1-conv projections -> packed bf16 workspaces.
// Output-role split: 768 WGs x 128 threads; og = bx>>7 selects role
// {0:f, 1:g, 2..5: V rows}. XT=true: x reads from xT (contiguous 256 B);
// XT=false: R13 fallback (strided) if ws_size too small for xT.
template<bool XT>
__global__ __launch_bounds__(128) void proj_kernel(
    const float* __restrict__ xsrc,
    const float* __restrict__ Wf, const float* __restrict__ bf,
    const float* __restrict__ Wg, const float* __restrict__ bg,
    const float* __restrict__ Wh, const float* __restrict__ bh,
    unsigned short* __restrict__ fpk,
    unsigned short* __restrict__ gpk,
    unsigned short* __restrict__ vblk)
{
    __shared__ float swT[CC][8];       // [c][o], 2 KB

    int tid = threadIdx.x;
    int bx  = blockIdx.x;
    int og  = bx >> 7;                 // 0..5 (block-uniform)
    int p   = (bx & 127) * 128 + tid;  // 0..16383
    int b = p >> 12;
    int n = p & (NN - 1);

    const float* W;
    const float* bias;
    if (og == 0)      { W = Wf; bias = bf; }
    else if (og == 1) { W = Wg; bias = bg; }
    else              { W = Wh + (og - 2) * 8 * CC; bias = bh + (og - 2) * 8; }

    // stage W -> LDS transposed (one-time)
    {
        float4 wv = *(const float4*)(W + tid * 4);   // coalesced
        int o = (tid * 4) >> 6;
        int c0 = (tid * 4) & 63;
        swT[c0 + 0][o] = wv.x;
        swT[c0 + 1][o] = wv.y;
        swT[c0 + 2][o] = wv.z;
        swT[c0 + 3][o] = wv.w;
    }

    // x loads: contiguous float4s (XT) or strided fallback; pin live.
    float xv[CC];
    if constexpr (XT) {
        const float4* xp4 = (const float4*)(xsrc + (size_t)p * CC);
        #pragma unroll
        for (int i = 0; i < 16; i++) ((float4*)xv)[i] = xp4[i];
    } else {
        const float* xp = xsrc + (size_t)b * CC * NN + n;
        #pragma unroll
        for (int c = 0; c < CC; c++) xv[c] = xp[(size_t)c * NN];
    }
    #pragma unroll
    for (int c = 0; c < CC; c++) asm volatile("" : "+v"(xv[c]));

    __syncthreads();

    float a[8];
    #pragma unroll
    for (int o = 0; o < 8; o++) a[o] = bias[o];
    #pragma unroll
    for (int c = 0; c < CC; c++) {
        float4 w0 = *(const float4*)&swT[c][0];   // ds_read_b128, broadcast
        float4 w1 = *(const float4*)&swT[c][4];
        float v = xv[c];
        a[0] += w0.x * v; a[1] += w0.y * v; a[2] += w0.z * v; a[3] += w0.w * v;
        a[4] += w1.x * v; a[5] += w1.y * v; a[6] += w1.z * v; a[7] += w1.w * v;
    }

    const float LOG2E = 1.4426950408889634f;
    size_t base = (size_t)b * NN + n;

    if (og == 0) {
        union { unsigned short s[16]; uint4 q[2]; } fo;
        #pragma unroll
        for (int o = 0; o < 8; o++) {
            unsigned short hi = f2bf(a[o]);
            unsigned short lo = f2bf(a[o] - bf2f(hi));
            fo.s[o] = hi; fo.s[8 + o] = lo;
        }
        uint4* fdst = (uint4*)(fpk + base * 16);
        fdst[0] = fo.q[0]; fdst[1] = fo.q[1];
    } else if (og == 1) {
        union { unsigned short s[32]; uint4 q[4]; } go;
        #pragma unroll
        for (int o = 0; o < 8; o++) {
            float gsc = a[o] * LOG2E;              // exp -> exp2 fold
            unsigned short hi = f2bf(gsc);
            unsigned short lo = f2bf(gsc - bf2f(hi));
            go.s[o] = hi; go.s[8 + o] = hi; go.s[16 + o] = lo; go.s[24 + o] = lo;
        }
        uint4* gdst = (uint4*)(gpk + base * 32);
        #pragma unroll
        for (int k = 0; k < 4; k++) gdst[k] = go.q[k];
    } else {
        int m5 = n & 31;
        int code = (m5 & 3) | (((m5 >> 4) & 1) << 2) | (((m5 >> 2) & 3) << 3);
        int mb = (n >> 5);                          // m-block within batch
        int h0 = (og - 2) * 8;
        int hg = h0 >> 4;                           // block-uniform
        unsigned short* vp = vblk + (size_t)b * (NN/32) * 1024
                           + (size_t)mb * 1024 + hg * 512 + code;
        #pragma unroll
        for (int o = 0; o < 8; o++)
            vp[((h0 + o) & 15) * 32] = f2bf(a[o]);
    }
}

// Kernel 2: register-only MFMA flash attention + fused Wv/gamma/residual.
// (unchanged R13) QBLK=32: 512 WGs -> 4 waves/SIMD; ~90 VGPR bounded by
// __launch_bounds__(512,4); XCD-swizzled blockIdx; deterministic combine;
// V reads from the 2 KB-blocked vblk layout.
__global__ __launch_bounds__(THREADS, 4) void attn_kernel(
    const unsigned short* __restrict__ fpk,
    const unsigned short* __restrict__ gpk,
    const unsigned short* __restrict__ vblk,
    const float* __restrict__ Wv, const float* __restrict__ bv,
    const float* __restrict__ gamma,
    const float* __restrict__ x, float* __restrict__ out)
{
    __shared__ float sl[WAVES][QBLK][HF + 1];   // 33.8 KB

    int tid  = threadIdx.x;
    int wave = tid >> 6;
    int lane = tid & 63;
    int c15  = lane & 15;
    int g4   = lane >> 4;

    // bijective XCD swizzle: 512 blocks = 8 XCD x 64 contiguous logical ids
    int l  = (blockIdx.x & 7) * 64 + (blockIdx.x >> 3);
    int b  = l >> 7;                  // 128 q-tiles per batch
    int n0 = (l & 127) * QBLK;

    bf16x8 bq[2];
    #pragma unroll
    for (int qg = 0; qg < 2; qg++)
        bq[qg] = *(const bf16x8*)(fpk
                  + ((size_t)(b * NN + n0 + qg*16 + c15)) * 16 + (g4 & 1) * 8);

    f32x4 zero4 = {0.f, 0.f, 0.f, 0.f};
    f32x4 acc[2][2];
    float Lacc[2] = {0.f, 0.f};
    #pragma unroll
    for (int qg = 0; qg < 2; qg++) { acc[qg][0] = zero4; acc[qg][1] = zero4; }

    const unsigned short* gsrc = gpk  + (size_t)b * NN * 32;
    const unsigned short* vsrc = vblk + (size_t)b * (NN/32) * 1024;
    int mbase = wave * MCHUNK;
    int mb0   = wave * NBLK;

    bf16x8 akc[2], vbc[2];
    {
        int m0 = mbase;
        akc[0] = *(const bf16x8*)(gsrc + (size_t)(m0 + c15)      * 32 + g4*8);
        akc[1] = *(const bf16x8*)(gsrc + (size_t)(m0 + 16 + c15) * 32 + g4*8);
        const unsigned short* vb = vsrc + (size_t)mb0 * 1024 + c15*32 + g4*8;
        vbc[0] = *(const bf16x8*)(vb);
        vbc[1] = *(const bf16x8*)(vb + 512);
    }

    #pragma unroll 2
    for (int t = 0; t < NBLK; t++) {
        bf16x8 akn[2], vbn[2];
        if (t + 1 < NBLK) {
            int m1 = mbase + (t + 1) * MBLK;
            akn[0] = *(const bf16x8*)(gsrc + (size_t)(m1 + c15)      * 32 + g4*8);
            akn[1] = *(const bf16x8*)(gsrc + (size_t)(m1 + 16 + c15) * 32 + g4*8);
            const unsigned short* vb = vsrc + (size_t)(mb0 + t + 1) * 1024
                                     + c15*32 + g4*8;
            vbn[0] = *(const bf16x8*)(vb);
            vbn[1] = *(const bf16x8*)(vb + 512);
        }

        // swapped QK^T: D[m-row][q-col]; exact hi/lo product
        f32x4 sf[2][2];
        #pragma unroll
        for (int mg = 0; mg < 2; mg++)
            #pragma unroll
            for (int qg = 0; qg < 2; qg++)
                sf[qg][mg] = __builtin_amdgcn_mfma_f32_16x16x32_bf16(
                    akc[mg], bq[qg], zero4, 0, 0, 0);

        // exp2 (log2e pre-folded), pack into PV A-fragment (k=r+4*mg+8*g4)
        bf16x8 pa[2];
        #pragma unroll
        for (int qg = 0; qg < 2; qg++) {
            float e00 = ex2(sf[qg][0][0]), e01 = ex2(sf[qg][0][1]);
            float e02 = ex2(sf[qg][0][2]), e03 = ex2(sf[qg][0][3]);
            float e10 = ex2(sf[qg][1][0]), e11 = ex2(sf[qg][1][1]);
            float e12 = ex2(sf[qg][1][2]), e13 = ex2(sf[qg][1][3]);
            Lacc[qg] += ((e00 + e01) + (e02 + e03)) + ((e10 + e11) + (e12 + e13));
            union { unsigned int u[4]; bf16x8 v; } pp;
            pp.u[0] = pk2(e00, e01); pp.u[1] = pk2(e02, e03);
            pp.u[2] = pk2(e10, e11); pp.u[3] = pk2(e12, e13);
            pa[qg] = pp.v;
        }

        // P * V: acc[qg][hg], D: col=c15=h, row=g4*4+r=q
        #pragma unroll
        for (int qg = 0; qg < 2; qg++)
            #pragma unroll
            for (int hg = 0; hg < 2; hg++)
                acc[qg][hg] = __builtin_amdgcn_mfma_f32_16x16x32_bf16(
                    pa[qg], vbc[hg], acc[qg][hg], 0, 0, 0);

        if (t + 1 < NBLK) {
            akc[0] = akn[0]; akc[1] = akn[1];
            vbc[0] = vbn[0]; vbc[1] = vbn[1];
        }
    }

    // ---- deterministic wave combine (no atomics) ----
    #pragma unroll
    for (int qg = 0; qg < 2; qg++)
        #pragma unroll
        for (int hg = 0; hg < 2; hg++)
            #pragma unroll
            for (int r = 0; r < 4; r++)
                sl[wave][qg*16 + g4*4 + r][hg*16 + c15] = acc[qg][hg][r];
    #pragma unroll
    for (int qg = 0; qg < 2; qg++) {
        float t = Lacc[qg];
        t += __shfl_xor(t, 16);
        t += __shfl_xor(t, 32);
        if (g4 == 0) sl[wave][qg*16 + c15][HF] = t;
    }
    __syncthreads();

    {
        int q = tid & 31;
        for (int col = tid >> 5; col < HF + 1; col += 16) {
            float s = sl[0][q][col];
            #pragma unroll
            for (int w2 = 1; w2 < WAVES; w2++) s += sl[w2][q][col];
            sl[0][q][col] = s;
        }
    }
    __syncthreads();

    // epilogue: normalize, Wv projection, gamma, residual
    int q  = tid & 31;
    int cb = tid >> 5;
    float rL = 1.f / sl[0][q][HF];
    float o_[HF];
    #pragma unroll
    for (int h = 0; h < HF; h++) o_[h] = sl[0][q][h] * rL;
    float gm = gamma[0];
    size_t obase = (size_t)b * CC * NN + n0 + q;
    for (int c = cb*4; c < cb*4 + 4; c++) {
        float v = bv[c];
        #pragma unroll
        for (int h = 0; h < HF; h++) v += Wv[c*HF + h] * o_[h];
        size_t a = obase + (size_t)c * NN;
        out[a] = gm * v + x[a];
    }
}

extern "C" void kernel_launch(void* const* d_in, const int* in_sizes, int n_in,
                              void* d_out, int out_size, void* d_ws, size_t ws_size,
                              hipStream_t stream) {
    const float* x     = (const float*)d_in[0];
    const float* Wf    = (const float*)d_in[1];
    const float* bf    = (const float*)d_in[2];
    const float* Wg    = (const float*)d_in[3];
    const float* bg    = (const float*)d_in[4];
    const float* Wh    = (const float*)d_in[5];
    const float* bh    = (const float*)d_in[6];
    const float* Wv    = (const float*)d_in[7];
    const float* bv    = (const float*)d_in[8];
    const float* gamma = (const float*)d_in[9];
    float* out = (float*)d_out;

    unsigned short* ws   = (unsigned short*)d_ws;
    unsigned short* fpk  = ws;                               // B*N*16  u16
    unsigned short* gpk  = ws + (size_t)BB*NN*16;            // B*N*32  u16
    unsigned short* vblk = ws + (size_t)BB*NN*48;            // B*128*1024 u16
    size_t base_u16 = (size_t)BB*NN*48 + (size_t)BB*(NN/32)*1024;  // 1,310,720
    float* xT = (float*)(ws + base_u16);                     // B*N*C f32
    size_t needed = base_u16 * 2 + (size_t)BB * NN * CC * 4; // ~19.4 MB

    if (ws_size >= needed) {
        xpose_kernel<<<512, 256, 0, stream>>>(x, xT);
        proj_kernel<true><<<(BB*NN/128)*6, 128, 0, stream>>>(
            xT, Wf, bf, Wg, bg, Wh, bh, fpk, gpk, vblk);
    } else {
        proj_kernel<false><<<(BB*NN/128)*6, 128, 0, stream>>>(
            x, Wf, bf, Wg, bg, Wh, bh, fpk, gpk, vblk);
    }
    attn_kernel<<<BB*(NN/QBLK), THREADS, 0, stream>>>(fpk, gpk, vblk,
                                                      Wv, bv, gamma, x, out);
}

// Round 15
// 39.749 us; speedup vs baseline: 1.0066x; 1.0066x over previous
//
#include <hip/hip_runtime.h>
#include <math.h>

#define BB 4
#define CC 64
#define NN 4096
#define IND 8
#define HF 32
#define QBLK 32
#define THREADS 512
#define WAVES 8
#define MBLK 32
#define MCHUNK (NN/WAVES)    // 512 m's per wave
#define NBLK (MCHUNK/MBLK)   // 16 blocks

typedef __attribute__((ext_vector_type(8))) short bf16x8;
typedef __attribute__((ext_vector_type(4))) float f32x4;

static __device__ __forceinline__ unsigned short f2bf(float x) {
    unsigned int u = __float_as_uint(x);
    u = (u + 0x7FFFu + ((u >> 16) & 1u)) >> 16;   // RNE
    return (unsigned short)u;
}
static __device__ __forceinline__ float bf2f(unsigned short h) {
    return __uint_as_float(((unsigned int)h) << 16);
}
static __device__ __forceinline__ unsigned int pk2(float lo, float hi) {
    return (unsigned int)f2bf(lo) | ((unsigned int)f2bf(hi) << 16);
}
static __device__ __forceinline__ float ex2(float x) {
    return __builtin_amdgcn_exp2f(x);   // v_exp_f32 (2^x)
}

// m -> k-slot coding shared by P (in-register) and V (blocked layout):
// k(m5) = (m5&3) | ((m5>>4)&1)<<2 | ((m5>>2)&3)<<3   (bijective on 0..31)
//
// V layout: vblk[b][mb][hg][c15][ks] u16 (2 KB per mb) -> contiguous wave-load.
// x channel fix: proj's 64 loads/thread at 16 KB stride ran ~1.3 TB/s (L2
// channel aliasing). Transpose x once -> xT[b][n][c]; proj reads contiguous.
// R14's xpose had scattered 32-B writes (regression); R15 uses LDS-tiled
// transpose: coalesced 256-B row reads, coalesced 4-KB wave writes.

// Kernel 0: x [B][C][N] -> xT [B][N][C]. 256 WGs x 256 threads; 64x64 f32
// tile via LDS [64][65] (2-way bank alias max = free).
__global__ __launch_bounds__(256) void xpose_kernel(
    const float* __restrict__ x, float* __restrict__ xT)
{
    __shared__ float tile[64][65];
    int bx = blockIdx.x;
    int b  = bx >> 6;
    int n0 = (bx & 63) * 64;
    int t  = threadIdx.x;

    // read: wave-contiguous 256-B rows
    int nl = t & 63;
    int c0 = (t >> 6) * 16;
    const float* xp = x + (size_t)b * CC * NN + n0 + nl;
    #pragma unroll
    for (int i = 0; i < 16; i++)
        tile[c0 + i][nl] = xp[(size_t)(c0 + i) * NN];
    __syncthreads();

    // write: threads t..t+3 cover one 256-B xT row; wave = 4 KB contiguous
    int nw = t >> 2;
    int cw = (t & 3) * 16;
    float4* dst = (float4*)(xT + ((size_t)(b * NN) + n0 + nw) * CC + cw);
    #pragma unroll
    for (int j = 0; j < 4; j++)
        dst[j] = make_float4(tile[cw + j*4 + 0][nw], tile[cw + j*4 + 1][nw],
                             tile[cw + j*4 + 2][nw], tile[cw + j*4 + 3][nw]);
}

// Kernel 1: 1x1-conv projections -> packed bf16 workspaces.
// Output-role split: 768 WGs x 128 threads; og = bx>>7 selects role
// {0:f, 1:g, 2..5: V rows}. XT=true: x reads from xT (contiguous);
// XT=false: strided fallback if ws too small.
template<bool XT>
__global__ __launch_bounds__(128) void proj_kernel(
    const float* __restrict__ xsrc,
    const float* __restrict__ Wf, const float* __restrict__ bf,
    const float* __restrict__ Wg, const float* __restrict__ bg,
    const float* __restrict__ Wh, const float* __restrict__ bh,
    unsigned short* __restrict__ fpk,
    unsigned short* __restrict__ gpk,
    unsigned short* __restrict__ vblk)
{
    __shared__ float swT[CC][8];       // [c][o], 2 KB

    int tid = threadIdx.x;
    int bx  = blockIdx.x;
    int og  = bx >> 7;                 // 0..5 (block-uniform)
    int p   = (bx & 127) * 128 + tid;  // 0..16383
    int b = p >> 12;
    int n = p & (NN - 1);

    const float* W;
    const float* bias;
    if (og == 0)      { W = Wf; bias = bf; }
    else if (og == 1) { W = Wg; bias = bg; }
    else              { W = Wh + (og - 2) * 8 * CC; bias = bh + (og - 2) * 8; }

    // stage W -> LDS transposed (one-time)
    {
        float4 wv = *(const float4*)(W + tid * 4);   // coalesced
        int o = (tid * 4) >> 6;
        int c0 = (tid * 4) & 63;
        swT[c0 + 0][o] = wv.x;
        swT[c0 + 1][o] = wv.y;
        swT[c0 + 2][o] = wv.z;
        swT[c0 + 3][o] = wv.w;
    }

    // x loads: contiguous float4s (XT) or strided fallback; pin live.
    float xv[CC];
    if constexpr (XT) {
        const float4* xp4 = (const float4*)(xsrc + (size_t)p * CC);
        #pragma unroll
        for (int i = 0; i < 16; i++) ((float4*)xv)[i] = xp4[i];
    } else {
        const float* xp = xsrc + (size_t)b * CC * NN + n;
        #pragma unroll
        for (int c = 0; c < CC; c++) xv[c] = xp[(size_t)c * NN];
    }
    #pragma unroll
    for (int c = 0; c < CC; c++) asm volatile("" : "+v"(xv[c]));

    __syncthreads();

    float a[8];
    #pragma unroll
    for (int o = 0; o < 8; o++) a[o] = bias[o];
    #pragma unroll
    for (int c = 0; c < CC; c++) {
        float4 w0 = *(const float4*)&swT[c][0];   // ds_read_b128, broadcast
        float4 w1 = *(const float4*)&swT[c][4];
        float v = xv[c];
        a[0] += w0.x * v; a[1] += w0.y * v; a[2] += w0.z * v; a[3] += w0.w * v;
        a[4] += w1.x * v; a[5] += w1.y * v; a[6] += w1.z * v; a[7] += w1.w * v;
    }

    const float LOG2E = 1.4426950408889634f;
    size_t base = (size_t)b * NN + n;

    if (og == 0) {
        union { unsigned short s[16]; uint4 q[2]; } fo;
        #pragma unroll
        for (int o = 0; o < 8; o++) {
            unsigned short hi = f2bf(a[o]);
            unsigned short lo = f2bf(a[o] - bf2f(hi));
            fo.s[o] = hi; fo.s[8 + o] = lo;
        }
        uint4* fdst = (uint4*)(fpk + base * 16);
        fdst[0] = fo.q[0]; fdst[1] = fo.q[1];
    } else if (og == 1) {
        union { unsigned short s[32]; uint4 q[4]; } go;
        #pragma unroll
        for (int o = 0; o < 8; o++) {
            float gsc = a[o] * LOG2E;              // exp -> exp2 fold
            unsigned short hi = f2bf(gsc);
            unsigned short lo = f2bf(gsc - bf2f(hi));
            go.s[o] = hi; go.s[8 + o] = hi; go.s[16 + o] = lo; go.s[24 + o] = lo;
        }
        uint4* gdst = (uint4*)(gpk + base * 32);
        #pragma unroll
        for (int k = 0; k < 4; k++) gdst[k] = go.q[k];
    } else {
        int m5 = n & 31;
        int code = (m5 & 3) | (((m5 >> 4) & 1) << 2) | (((m5 >> 2) & 3) << 3);
        int mb = (n >> 5);                          // m-block within batch
        int h0 = (og - 2) * 8;
        int hg = h0 >> 4;                           // block-uniform
        unsigned short* vp = vblk + (size_t)b * (NN/32) * 1024
                           + (size_t)mb * 1024 + hg * 512 + code;
        #pragma unroll
        for (int o = 0; o < 8; o++)
            vp[((h0 + o) & 15) * 32] = f2bf(a[o]);
    }
}

// Kernel 2: register-only MFMA flash attention + fused Wv/gamma/residual.
// (unchanged R13) QBLK=32: 512 WGs -> 4 waves/SIMD; ~90 VGPR bounded by
// __launch_bounds__(512,4); XCD-swizzled blockIdx; deterministic combine;
// V reads from the 2 KB-blocked vblk layout.
__global__ __launch_bounds__(THREADS, 4) void attn_kernel(
    const unsigned short* __restrict__ fpk,
    const unsigned short* __restrict__ gpk,
    const unsigned short* __restrict__ vblk,
    const float* __restrict__ Wv, const float* __restrict__ bv,
    const float* __restrict__ gamma,
    const float* __restrict__ x, float* __restrict__ out)
{
    __shared__ float sl[WAVES][QBLK][HF + 1];   // 33.8 KB

    int tid  = threadIdx.x;
    int wave = tid >> 6;
    int lane = tid & 63;
    int c15  = lane & 15;
    int g4   = lane >> 4;

    // bijective XCD swizzle: 512 blocks = 8 XCD x 64 contiguous logical ids
    int l  = (blockIdx.x & 7) * 64 + (blockIdx.x >> 3);
    int b  = l >> 7;                  // 128 q-tiles per batch
    int n0 = (l & 127) * QBLK;

    bf16x8 bq[2];
    #pragma unroll
    for (int qg = 0; qg < 2; qg++)
        bq[qg] = *(const bf16x8*)(fpk
                  + ((size_t)(b * NN + n0 + qg*16 + c15)) * 16 + (g4 & 1) * 8);

    f32x4 zero4 = {0.f, 0.f, 0.f, 0.f};
    f32x4 acc[2][2];
    float Lacc[2] = {0.f, 0.f};
    #pragma unroll
    for (int qg = 0; qg < 2; qg++) { acc[qg][0] = zero4; acc[qg][1] = zero4; }

    const unsigned short* gsrc = gpk  + (size_t)b * NN * 32;
    const unsigned short* vsrc = vblk + (size_t)b * (NN/32) * 1024;
    int mbase = wave * MCHUNK;
    int mb0   = wave * NBLK;

    bf16x8 akc[2], vbc[2];
    {
        int m0 = mbase;
        akc[0] = *(const bf16x8*)(gsrc + (size_t)(m0 + c15)      * 32 + g4*8);
        akc[1] = *(const bf16x8*)(gsrc + (size_t)(m0 + 16 + c15) * 32 + g4*8);
        const unsigned short* vb = vsrc + (size_t)mb0 * 1024 + c15*32 + g4*8;
        vbc[0] = *(const bf16x8*)(vb);
        vbc[1] = *(const bf16x8*)(vb + 512);
    }

    #pragma unroll 2
    for (int t = 0; t < NBLK; t++) {
        bf16x8 akn[2], vbn[2];
        if (t + 1 < NBLK) {
            int m1 = mbase + (t + 1) * MBLK;
            akn[0] = *(const bf16x8*)(gsrc + (size_t)(m1 + c15)      * 32 + g4*8);
            akn[1] = *(const bf16x8*)(gsrc + (size_t)(m1 + 16 + c15) * 32 + g4*8);
            const unsigned short* vb = vsrc + (size_t)(mb0 + t + 1) * 1024
                                     + c15*32 + g4*8;
            vbn[0] = *(const bf16x8*)(vb);
            vbn[1] = *(const bf16x8*)(vb + 512);
        }

        // swapped QK^T: D[m-row][q-col]; exact hi/lo product
        f32x4 sf[2][2];
        #pragma unroll
        for (int mg = 0; mg < 2; mg++)
            #pragma unroll
            for (int qg = 0; qg < 2; qg++)
                sf[qg][mg] = __builtin_amdgcn_mfma_f32_16x16x32_bf16(
                    akc[mg], bq[qg], zero4, 0, 0, 0);

        // exp2 (log2e pre-folded), pack into PV A-fragment (k=r+4*mg+8*g4)
        bf16x8 pa[2];
        #pragma unroll
        for (int qg = 0; qg < 2; qg++) {
            float e00 = ex2(sf[qg][0][0]), e01 = ex2(sf[qg][0][1]);
            float e02 = ex2(sf[qg][0][2]), e03 = ex2(sf[qg][0][3]);
            float e10 = ex2(sf[qg][1][0]), e11 = ex2(sf[qg][1][1]);
            float e12 = ex2(sf[qg][1][2]), e13 = ex2(sf[qg][1][3]);
            Lacc[qg] += ((e00 + e01) + (e02 + e03)) + ((e10 + e11) + (e12 + e13));
            union { unsigned int u[4]; bf16x8 v; } pp;
            pp.u[0] = pk2(e00, e01); pp.u[1] = pk2(e02, e03);
            pp.u[2] = pk2(e10, e11); pp.u[3] = pk2(e12, e13);
            pa[qg] = pp.v;
        }

        // P * V: acc[qg][hg], D: col=c15=h, row=g4*4+r=q
        #pragma unroll
        for (int qg = 0; qg < 2; qg++)
            #pragma unroll
            for (int hg = 0; hg < 2; hg++)
                acc[qg][hg] = __builtin_amdgcn_mfma_f32_16x16x32_bf16(
                    pa[qg], vbc[hg], acc[qg][hg], 0, 0, 0);

        if (t + 1 < NBLK) {
            akc[0] = akn[0]; akc[1] = akn[1];
            vbc[0] = vbn[0]; vbc[1] = vbn[1];
        }
    }

    // ---- deterministic wave combine (no atomics) ----
    #pragma unroll
    for (int qg = 0; qg < 2; qg++)
        #pragma unroll
        for (int hg = 0; hg < 2; hg++)
            #pragma unroll
            for (int r = 0; r < 4; r++)
                sl[wave][qg*16 + g4*4 + r][hg*16 + c15] = acc[qg][hg][r];
    #pragma unroll
    for (int qg = 0; qg < 2; qg++) {
        float t = Lacc[qg];
        t += __shfl_xor(t, 16);
        t += __shfl_xor(t, 32);
        if (g4 == 0) sl[wave][qg*16 + c15][HF] = t;
    }
    __syncthreads();

    {
        int q = tid & 31;
        for (int col = tid >> 5; col < HF + 1; col += 16) {
            float s = sl[0][q][col];
            #pragma unroll
            for (int w2 = 1; w2 < WAVES; w2++) s += sl[w2][q][col];
            sl[0][q][col] = s;
        }
    }
    __syncthreads();

    // epilogue: normalize, Wv projection, gamma, residual
    int q  = tid & 31;
    int cb = tid >> 5;
    float rL = 1.f / sl[0][q][HF];
    float o_[HF];
    #pragma unroll
    for (int h = 0; h < HF; h++) o_[h] = sl[0][q][h] * rL;
    float gm = gamma[0];
    size_t obase = (size_t)b * CC * NN + n0 + q;
    for (int c = cb*4; c < cb*4 + 4; c++) {
        float v = bv[c];
        #pragma unroll
        for (int h = 0; h < HF; h++) v += Wv[c*HF + h] * o_[h];
        size_t a = obase + (size_t)c * NN;
        out[a] = gm * v + x[a];
    }
}

extern "C" void kernel_launch(void* const* d_in, const int* in_sizes, int n_in,
                              void* d_out, int out_size, void* d_ws, size_t ws_size,
                              hipStream_t stream) {
    const float* x     = (const float*)d_in[0];
    const float* Wf    = (const float*)d_in[1];
    const float* bf    = (const float*)d_in[2];
    const float* Wg    = (const float*)d_in[3];
    const float* bg    = (const float*)d_in[4];
    const float* Wh    = (const float*)d_in[5];
    const float* bh    = (const float*)d_in[6];
    const float* Wv    = (const float*)d_in[7];
    const float* bv    = (const float*)d_in[8];
    const float* gamma = (const float*)d_in[9];
    float* out = (float*)d_out;

    unsigned short* ws   = (unsigned short*)d_ws;
    unsigned short* fpk  = ws;                               // B*N*16  u16
    unsigned short* gpk  = ws + (size_t)BB*NN*16;            // B*N*32  u16
    unsigned short* vblk = ws + (size_t)BB*NN*48;            // B*128*1024 u16
    size_t base_u16 = (size_t)BB*NN*48 + (size_t)BB*(NN/32)*1024;  // 1,310,720
    float* xT = (float*)(ws + base_u16);                     // B*N*C f32 (4 MB)
    size_t needed = base_u16 * 2 + (size_t)BB * NN * CC * 4; // ~6.6 MB

    if (ws_size >= needed) {
        xpose_kernel<<<BB*(NN/64), 256, 0, stream>>>(x, xT);
        proj_kernel<true><<<(BB*NN/128)*6, 128, 0, stream>>>(
            xT, Wf, bf, Wg, bg, Wh, bh, fpk, gpk, vblk);
    } else {
        proj_kernel<false><<<(BB*NN/128)*6, 128, 0, stream>>>(
            x, Wf, bf, Wg, bg, Wh, bh, fpk, gpk, vblk);
    }
    attn_kernel<<<BB*(NN/QBLK), THREADS, 0, stream>>>(fpk, gpk, vblk,
                                                      Wv, bv, gamma, x, out);
}

// Round 16
// 34.124 us; speedup vs baseline: 1.1725x; 1.1648x over previous
//
#include <hip/hip_runtime.h>
#include <math.h>

#define BB 4
#define CC 64
#define NN 4096
#define IND 8
#define HF 32
#define QBLK 32
#define THREADS 512
#define WAVES 8
#define MBLK 32
#define MCHUNK (NN/WAVES)    // 512 m's per wave
#define NBLK (MCHUNK/MBLK)   // 16 blocks

typedef __attribute__((ext_vector_type(8))) short bf16x8;
typedef __attribute__((ext_vector_type(4))) float f32x4;

static __device__ __forceinline__ unsigned short f2bf(float x) {
    unsigned int u = __float_as_uint(x);
    u = (u + 0x7FFFu + ((u >> 16) & 1u)) >> 16;   // RNE
    return (unsigned short)u;
}
static __device__ __forceinline__ float bf2f(unsigned short h) {
    return __uint_as_float(((unsigned int)h) << 16);
}
static __device__ __forceinline__ unsigned int pk2(float lo, float hi) {
    return (unsigned int)f2bf(lo) | ((unsigned int)f2bf(hi) << 16);
}
static __device__ __forceinline__ float ex2(float x) {
    return __builtin_amdgcn_exp2f(x);   // v_exp_f32 (2^x)
}

// m -> k-slot coding shared by P (in-register) and V (blocked layout):
// k(m5) = (m5&3) | ((m5>>4)&1)<<2 | ((m5>>2)&3)<<3   (bijective on 0..31)
// V layout: vblk[b][mb][hg][c15][ks] u16 (2 KB per mb) -> contiguous wave-load.

// Kernel 1 (R16 rewrite): ONE-PASS projections. 256 WGs x 256 threads;
// WG owns 64 positions. x staged once via coalesced row reads (6 MB total,
// was 24 MB over 6 role-reads); all W transposed in LDS; wave role split
// {0:f, 1:g, 2:hv[0..15], 3:hv[16..31]}. V goes through LDS vtile then out
// as two coalesced 2 KB blocks -- kills proj's 2-byte scattered V stores
// (~16x write amplification, the hidden cost of R9-R15 proj).
__global__ __launch_bounds__(256) void proj_kernel(
    const float* __restrict__ x,
    const float* __restrict__ Wf, const float* __restrict__ bf,
    const float* __restrict__ Wg, const float* __restrict__ bg,
    const float* __restrict__ Wh, const float* __restrict__ bh,
    unsigned short* __restrict__ fpk,
    unsigned short* __restrict__ gpk,
    unsigned short* __restrict__ vblk)
{
    __shared__ float xtile[CC][65];            // 16.25 KB, +1 pad
    __shared__ float wT[CC][52];               // 13 KB: [c][o] o: 0-7 f, 8-15 g, 16-47 hv
    __shared__ unsigned short vtile[2][1024];  // 4 KB: two 2 KB V blocks

    int tid = threadIdx.x;
    int bx  = blockIdx.x;
    int b   = bx >> 6;
    int n0  = (bx & 63) * 64;

    // stage weights transposed (coalesced global reads; LDS scatter 2-way max)
    for (int idx = tid; idx < IND*CC; idx += 256) {
        int o = idx >> 6, c = idx & 63;
        wT[c][o]     = Wf[idx];
        wT[c][8 + o] = Wg[idx];
    }
    for (int idx = tid; idx < HF*CC; idx += 256) {
        int o = idx >> 6, c = idx & 63;
        wT[c][16 + o] = Wh[idx];
    }
    // stage x rows: lanes = consecutive n -> coalesced 256 B per instruction
    {
        const float* xb = x + (size_t)b * CC * NN + n0;
        for (int idx = tid; idx < CC*64; idx += 256) {
            int c = idx >> 6, nl = idx & 63;
            xtile[c][nl] = xb[(size_t)c * NN + nl];
        }
    }
    __syncthreads();

    int wave = tid >> 6;
    int nl   = tid & 63;
    int n    = n0 + nl;
    size_t base = (size_t)b * NN + n;
    const float LOG2E = 1.4426950408889634f;

    if (wave == 0) {                 // f: hi/lo split -> fpk [n][16]
        float a[8];
        #pragma unroll
        for (int o = 0; o < 8; o++) a[o] = bf[o];
        for (int c = 0; c < CC; c++) {
            float v = xtile[c][nl];
            float4 w0 = *(const float4*)&wT[c][0];
            float4 w1 = *(const float4*)&wT[c][4];
            a[0] += w0.x*v; a[1] += w0.y*v; a[2] += w0.z*v; a[3] += w0.w*v;
            a[4] += w1.x*v; a[5] += w1.y*v; a[6] += w1.z*v; a[7] += w1.w*v;
        }
        union { unsigned short s[16]; uint4 q[2]; } fo;
        #pragma unroll
        for (int o = 0; o < 8; o++) {
            unsigned short hi = f2bf(a[o]);
            unsigned short lo = f2bf(a[o] - bf2f(hi));
            fo.s[o] = hi; fo.s[8 + o] = lo;
        }
        uint4* fdst = (uint4*)(fpk + base * 16);
        fdst[0] = fo.q[0]; fdst[1] = fo.q[1];
    } else if (wave == 1) {          // g: log2e-folded hi/lo -> gpk [n][32]
        float a[8];
        #pragma unroll
        for (int o = 0; o < 8; o++) a[o] = bg[o];
        for (int c = 0; c < CC; c++) {
            float v = xtile[c][nl];
            float4 w0 = *(const float4*)&wT[c][8];
            float4 w1 = *(const float4*)&wT[c][12];
            a[0] += w0.x*v; a[1] += w0.y*v; a[2] += w0.z*v; a[3] += w0.w*v;
            a[4] += w1.x*v; a[5] += w1.y*v; a[6] += w1.z*v; a[7] += w1.w*v;
        }
        union { unsigned short s[32]; uint4 q[4]; } go;
        #pragma unroll
        for (int o = 0; o < 8; o++) {
            float gsc = a[o] * LOG2E;
            unsigned short hi = f2bf(gsc);
            unsigned short lo = f2bf(gsc - bf2f(hi));
            go.s[o] = hi; go.s[8 + o] = hi; go.s[16 + o] = lo; go.s[24 + o] = lo;
        }
        uint4* gdst = (uint4*)(gpk + base * 32);
        #pragma unroll
        for (int k = 0; k < 4; k++) gdst[k] = go.q[k];
    } else {                         // hv halves -> vtile (LDS), coalesced out
        int hg = wave - 2;           // 0 or 1
        int h0 = hg * 16;
        float a[16];
        #pragma unroll
        for (int i = 0; i < 16; i++) a[i] = bh[h0 + i];
        for (int c = 0; c < CC; c++) {
            float v = xtile[c][nl];
            #pragma unroll
            for (int j = 0; j < 4; j++) {
                float4 w = *(const float4*)&wT[c][16 + h0 + j*4];
                a[j*4+0] += w.x*v; a[j*4+1] += w.y*v;
                a[j*4+2] += w.z*v; a[j*4+3] += w.w*v;
            }
        }
        int m5 = nl & 31;
        int code = (m5 & 3) | (((m5 >> 4) & 1) << 2) | (((m5 >> 2) & 3) << 3);
        int mb = nl >> 5;
        unsigned short* vp = &vtile[mb][hg * 512 + code];
        #pragma unroll
        for (int i = 0; i < 16; i++)
            vp[i * 32] = f2bf(a[i]);
    }
    __syncthreads();

    // V out: 2 blocks x 2 KB, 256 threads x 1 uint4 (fully coalesced)
    {
        int lmb = tid >> 7;                 // 0..1
        int off = (tid & 127) * 8;          // u16 offset
        uint4 v = *(uint4*)&vtile[lmb][off];
        *(uint4*)(vblk + ((size_t)(bx * 2 + lmb)) * 1024 + off) = v;
    }
}

// Kernel 2: register-only MFMA flash attention + fused Wv/gamma/residual.
// (unchanged R13) QBLK=32: 512 WGs -> 4 waves/SIMD; ~90 VGPR bounded by
// __launch_bounds__(512,4); XCD-swizzled blockIdx; deterministic combine;
// V reads from the 2 KB-blocked vblk layout.
__global__ __launch_bounds__(THREADS, 4) void attn_kernel(
    const unsigned short* __restrict__ fpk,
    const unsigned short* __restrict__ gpk,
    const unsigned short* __restrict__ vblk,
    const float* __restrict__ Wv, const float* __restrict__ bv,
    const float* __restrict__ gamma,
    const float* __restrict__ x, float* __restrict__ out)
{
    __shared__ float sl[WAVES][QBLK][HF + 1];   // 33.8 KB

    int tid  = threadIdx.x;
    int wave = tid >> 6;
    int lane = tid & 63;
    int c15  = lane & 15;
    int g4   = lane >> 4;

    // bijective XCD swizzle: 512 blocks = 8 XCD x 64 contiguous logical ids
    int l  = (blockIdx.x & 7) * 64 + (blockIdx.x >> 3);
    int b  = l >> 7;                  // 128 q-tiles per batch
    int n0 = (l & 127) * QBLK;

    bf16x8 bq[2];
    #pragma unroll
    for (int qg = 0; qg < 2; qg++)
        bq[qg] = *(const bf16x8*)(fpk
                  + ((size_t)(b * NN + n0 + qg*16 + c15)) * 16 + (g4 & 1) * 8);

    f32x4 zero4 = {0.f, 0.f, 0.f, 0.f};
    f32x4 acc[2][2];
    float Lacc[2] = {0.f, 0.f};
    #pragma unroll
    for (int qg = 0; qg < 2; qg++) { acc[qg][0] = zero4; acc[qg][1] = zero4; }

    const unsigned short* gsrc = gpk  + (size_t)b * NN * 32;
    const unsigned short* vsrc = vblk + (size_t)b * (NN/32) * 1024;
    int mbase = wave * MCHUNK;
    int mb0   = wave * NBLK;

    bf16x8 akc[2], vbc[2];
    {
        int m0 = mbase;
        akc[0] = *(const bf16x8*)(gsrc + (size_t)(m0 + c15)      * 32 + g4*8);
        akc[1] = *(const bf16x8*)(gsrc + (size_t)(m0 + 16 + c15) * 32 + g4*8);
        const unsigned short* vb = vsrc + (size_t)mb0 * 1024 + c15*32 + g4*8;
        vbc[0] = *(const bf16x8*)(vb);
        vbc[1] = *(const bf16x8*)(vb + 512);
    }

    #pragma unroll 2
    for (int t = 0; t < NBLK; t++) {
        bf16x8 akn[2], vbn[2];
        if (t + 1 < NBLK) {
            int m1 = mbase + (t + 1) * MBLK;
            akn[0] = *(const bf16x8*)(gsrc + (size_t)(m1 + c15)      * 32 + g4*8);
            akn[1] = *(const bf16x8*)(gsrc + (size_t)(m1 + 16 + c15) * 32 + g4*8);
            const unsigned short* vb = vsrc + (size_t)(mb0 + t + 1) * 1024
                                     + c15*32 + g4*8;
            vbn[0] = *(const bf16x8*)(vb);
            vbn[1] = *(const bf16x8*)(vb + 512);
        }

        // swapped QK^T: D[m-row][q-col]; exact hi/lo product
        f32x4 sf[2][2];
        #pragma unroll
        for (int mg = 0; mg < 2; mg++)
            #pragma unroll
            for (int qg = 0; qg < 2; qg++)
                sf[qg][mg] = __builtin_amdgcn_mfma_f32_16x16x32_bf16(
                    akc[mg], bq[qg], zero4, 0, 0, 0);

        // exp2 (log2e pre-folded), pack into PV A-fragment (k=r+4*mg+8*g4)
        bf16x8 pa[2];
        #pragma unroll
        for (int qg = 0; qg < 2; qg++) {
            float e00 = ex2(sf[qg][0][0]), e01 = ex2(sf[qg][0][1]);
            float e02 = ex2(sf[qg][0][2]), e03 = ex2(sf[qg][0][3]);
            float e10 = ex2(sf[qg][1][0]), e11 = ex2(sf[qg][1][1]);
            float e12 = ex2(sf[qg][1][2]), e13 = ex2(sf[qg][1][3]);
            Lacc[qg] += ((e00 + e01) + (e02 + e03)) + ((e10 + e11) + (e12 + e13));
            union { unsigned int u[4]; bf16x8 v; } pp;
            pp.u[0] = pk2(e00, e01); pp.u[1] = pk2(e02, e03);
            pp.u[2] = pk2(e10, e11); pp.u[3] = pk2(e12, e13);
            pa[qg] = pp.v;
        }

        // P * V: acc[qg][hg], D: col=c15=h, row=g4*4+r=q
        #pragma unroll
        for (int qg = 0; qg < 2; qg++)
            #pragma unroll
            for (int hg = 0; hg < 2; hg++)
                acc[qg][hg] = __builtin_amdgcn_mfma_f32_16x16x32_bf16(
                    pa[qg], vbc[hg], acc[qg][hg], 0, 0, 0);

        if (t + 1 < NBLK) {
            akc[0] = akn[0]; akc[1] = akn[1];
            vbc[0] = vbn[0]; vbc[1] = vbn[1];
        }
    }

    // ---- deterministic wave combine (no atomics) ----
    #pragma unroll
    for (int qg = 0; qg < 2; qg++)
        #pragma unroll
        for (int hg = 0; hg < 2; hg++)
            #pragma unroll
            for (int r = 0; r < 4; r++)
                sl[wave][qg*16 + g4*4 + r][hg*16 + c15] = acc[qg][hg][r];
    #pragma unroll
    for (int qg = 0; qg < 2; qg++) {
        float t = Lacc[qg];
        t += __shfl_xor(t, 16);
        t += __shfl_xor(t, 32);
        if (g4 == 0) sl[wave][qg*16 + c15][HF] = t;
    }
    __syncthreads();

    {
        int q = tid & 31;
        for (int col = tid >> 5; col < HF + 1; col += 16) {
            float s = sl[0][q][col];
            #pragma unroll
            for (int w2 = 1; w2 < WAVES; w2++) s += sl[w2][q][col];
            sl[0][q][col] = s;
        }
    }
    __syncthreads();

    // epilogue: normalize, Wv projection, gamma, residual
    int q  = tid & 31;
    int cb = tid >> 5;
    float rL = 1.f / sl[0][q][HF];
    float o_[HF];
    #pragma unroll
    for (int h = 0; h < HF; h++) o_[h] = sl[0][q][h] * rL;
    float gm = gamma[0];
    size_t obase = (size_t)b * CC * NN + n0 + q;
    for (int c = cb*4; c < cb*4 + 4; c++) {
        float v = bv[c];
        #pragma unroll
        for (int h = 0; h < HF; h++) v += Wv[c*HF + h] * o_[h];
        size_t a = obase + (size_t)c * NN;
        out[a] = gm * v + x[a];
    }
}

extern "C" void kernel_launch(void* const* d_in, const int* in_sizes, int n_in,
                              void* d_out, int out_size, void* d_ws, size_t ws_size,
                              hipStream_t stream) {
    const float* x     = (const float*)d_in[0];
    const float* Wf    = (const float*)d_in[1];
    const float* bf    = (const float*)d_in[2];
    const float* Wg    = (const float*)d_in[3];
    const float* bg    = (const float*)d_in[4];
    const float* Wh    = (const float*)d_in[5];
    const float* bh    = (const float*)d_in[6];
    const float* Wv    = (const float*)d_in[7];
    const float* bv    = (const float*)d_in[8];
    const float* gamma = (const float*)d_in[9];
    float* out = (float*)d_out;

    unsigned short* ws   = (unsigned short*)d_ws;
    unsigned short* fpk  = ws;                               // B*N*16  u16
    unsigned short* gpk  = ws + (size_t)BB*NN*16;            // B*N*32  u16
    unsigned short* vblk = ws + (size_t)BB*NN*48;            // B*128*1024 u16
    // total 2.62 MB

    proj_kernel<<<BB*(NN/64), 256, 0, stream>>>(x, Wf, bf, Wg, bg, Wh, bh,
                                                fpk, gpk, vblk);
    attn_kernel<<<BB*(NN/QBLK), THREADS, 0, stream>>>(fpk, gpk, vblk,
                                                      Wv, bv, gamma, x, out);
}

// Round 17
// 32.097 us; speedup vs baseline: 1.2466x; 1.0632x over previous
//
#include <hip/hip_runtime.h>
#include <math.h>

#define BB 4
#define CC 64
#define NN 4096
#define IND 8
#define HF 32
#define QBLK 32
#define THREADS 512
#define WAVES 8
#define MBLK 32
#define MCHUNK (NN/WAVES)    // 512 m's per wave
#define NBLK (MCHUNK/MBLK)   // 16 blocks

typedef __attribute__((ext_vector_type(8))) short bf16x8;
typedef __attribute__((ext_vector_type(4))) float f32x4;

static __device__ __forceinline__ unsigned short f2bf(float x) {
    unsigned int u = __float_as_uint(x);
    u = (u + 0x7FFFu + ((u >> 16) & 1u)) >> 16;   // RNE
    return (unsigned short)u;
}
static __device__ __forceinline__ float bf2f(unsigned short h) {
    return __uint_as_float(((unsigned int)h) << 16);
}
// R17: native __bf16 casts -> compiler emits v_cvt_pk_bf16_f32 (1 instr per
// pair) instead of ~10 integer ops per value (hand-rolled RNE was the
// largest VALU block in attn's inner loop).
static __device__ __forceinline__ unsigned int pk2(float lo, float hi) {
    __bf16 l = (__bf16)lo, h = (__bf16)hi;
    unsigned short ul = __builtin_bit_cast(unsigned short, l);
    unsigned short uh = __builtin_bit_cast(unsigned short, h);
    return (unsigned int)ul | ((unsigned int)uh << 16);
}
static __device__ __forceinline__ float ex2(float x) {
    return __builtin_amdgcn_exp2f(x);   // v_exp_f32 (2^x)
}

// m -> k-slot coding shared by P (in-register) and V (blocked layout):
// k(m5) = (m5&3) | ((m5>>4)&1)<<2 | ((m5>>2)&3)<<3   (bijective on 0..31)
// V layout: vblk[b][mb][hg][c15][ks] u16 (2 KB per mb) -> contiguous wave-load.

// Kernel 1: 1x1-conv projections -> packed bf16 workspaces. (R13 form --
// measured best; R16's one-pass rewrite was 1.2 us slower from wave imbalance)
template<bool XT_UNUSED = false>
__global__ __launch_bounds__(128) void proj_kernel(
    const float* __restrict__ xsrc,
    const float* __restrict__ Wf, const float* __restrict__ bf,
    const float* __restrict__ Wg, const float* __restrict__ bg,
    const float* __restrict__ Wh, const float* __restrict__ bh,
    unsigned short* __restrict__ fpk,
    unsigned short* __restrict__ gpk,
    unsigned short* __restrict__ vblk)
{
    __shared__ float swT[CC][8];       // [c][o], 2 KB

    int tid = threadIdx.x;
    int bx  = blockIdx.x;
    int og  = bx >> 7;                 // 0..5 (block-uniform)
    int p   = (bx & 127) * 128 + tid;  // 0..16383
    int b = p >> 12;
    int n = p & (NN - 1);

    const float* W;
    const float* bias;
    if (og == 0)      { W = Wf; bias = bf; }
    else if (og == 1) { W = Wg; bias = bg; }
    else              { W = Wh + (og - 2) * 8 * CC; bias = bh + (og - 2) * 8; }

    // stage W -> LDS transposed (one-time)
    {
        float4 wv = *(const float4*)(W + tid * 4);   // coalesced
        int o = (tid * 4) >> 6;
        int c0 = (tid * 4) & 63;
        swT[c0 + 0][o] = wv.x;
        swT[c0 + 1][o] = wv.y;
        swT[c0 + 2][o] = wv.z;
        swT[c0 + 3][o] = wv.w;
    }

    // issue all 64 coalesced loads, then pin them live before any FMA
    float xv[CC];
    {
        const float* xp = xsrc + (size_t)b * CC * NN + n;
        #pragma unroll
        for (int c = 0; c < CC; c++) xv[c] = xp[(size_t)c * NN];
    }
    #pragma unroll
    for (int c = 0; c < CC; c++) asm volatile("" : "+v"(xv[c]));

    __syncthreads();

    float a[8];
    #pragma unroll
    for (int o = 0; o < 8; o++) a[o] = bias[o];
    #pragma unroll
    for (int c = 0; c < CC; c++) {
        float4 w0 = *(const float4*)&swT[c][0];   // ds_read_b128, broadcast
        float4 w1 = *(const float4*)&swT[c][4];
        float v = xv[c];
        a[0] += w0.x * v; a[1] += w0.y * v; a[2] += w0.z * v; a[3] += w0.w * v;
        a[4] += w1.x * v; a[5] += w1.y * v; a[6] += w1.z * v; a[7] += w1.w * v;
    }

    const float LOG2E = 1.4426950408889634f;
    size_t base = (size_t)b * NN + n;

    if (og == 0) {
        union { unsigned short s[16]; uint4 q[2]; } fo;
        #pragma unroll
        for (int o = 0; o < 8; o++) {
            unsigned short hi = f2bf(a[o]);
            unsigned short lo = f2bf(a[o] - bf2f(hi));
            fo.s[o] = hi; fo.s[8 + o] = lo;
        }
        uint4* fdst = (uint4*)(fpk + base * 16);
        fdst[0] = fo.q[0]; fdst[1] = fo.q[1];
    } else if (og == 1) {
        union { unsigned short s[32]; uint4 q[4]; } go;
        #pragma unroll
        for (int o = 0; o < 8; o++) {
            float gsc = a[o] * LOG2E;              // exp -> exp2 fold
            unsigned short hi = f2bf(gsc);
            unsigned short lo = f2bf(gsc - bf2f(hi));
            go.s[o] = hi; go.s[8 + o] = hi; go.s[16 + o] = lo; go.s[24 + o] = lo;
        }
        uint4* gdst = (uint4*)(gpk + base * 32);
        #pragma unroll
        for (int k = 0; k < 4; k++) gdst[k] = go.q[k];
    } else {
        int m5 = n & 31;
        int code = (m5 & 3) | (((m5 >> 4) & 1) << 2) | (((m5 >> 2) & 3) << 3);
        int mb = (n >> 5);                          // m-block within batch
        int h0 = (og - 2) * 8;
        int hg = h0 >> 4;                           // block-uniform
        unsigned short* vp = vblk + (size_t)b * (NN/32) * 1024
                           + (size_t)mb * 1024 + hg * 512 + code;
        #pragma unroll
        for (int o = 0; o < 8; o++)
            vp[((h0 + o) & 15) * 32] = f2bf(a[o]);
    }
}

// Kernel 2: register-only MFMA flash attention + fused Wv/gamma/residual.
// R17 changes vs R13: (1) pk2 -> native __bf16 cvt (v_cvt_pk_bf16_f32 path,
// was ~80 VALU cyc/t of integer RNE); (2) L computed by 2 extra MFMA with a
// ones B-operand on the idle matrix pipe (was 16 VALU adds + 2 shfl per t).
__global__ __launch_bounds__(THREADS, 4) void attn_kernel(
    const unsigned short* __restrict__ fpk,
    const unsigned short* __restrict__ gpk,
    const unsigned short* __restrict__ vblk,
    const float* __restrict__ Wv, const float* __restrict__ bv,
    const float* __restrict__ gamma,
    const float* __restrict__ x, float* __restrict__ out)
{
    __shared__ float sl[WAVES][QBLK][HF + 1];   // 33.8 KB

    int tid  = threadIdx.x;
    int wave = tid >> 6;
    int lane = tid & 63;
    int c15  = lane & 15;
    int g4   = lane >> 4;

    // bijective XCD swizzle: 512 blocks = 8 XCD x 64 contiguous logical ids
    int l  = (blockIdx.x & 7) * 64 + (blockIdx.x >> 3);
    int b  = l >> 7;                  // 128 q-tiles per batch
    int n0 = (l & 127) * QBLK;

    bf16x8 bq[2];
    #pragma unroll
    for (int qg = 0; qg < 2; qg++)
        bq[qg] = *(const bf16x8*)(fpk
                  + ((size_t)(b * NN + n0 + qg*16 + c15)) * 16 + (g4 & 1) * 8);

    f32x4 zero4 = {0.f, 0.f, 0.f, 0.f};
    f32x4 acc[2][2];
    f32x4 accL[2];
    #pragma unroll
    for (int qg = 0; qg < 2; qg++) {
        acc[qg][0] = zero4; acc[qg][1] = zero4; accL[qg] = zero4;
    }
    const short one_bf = (short)0x3F80;   // 1.0 bf16
    const bf16x8 vones = {one_bf, one_bf, one_bf, one_bf,
                          one_bf, one_bf, one_bf, one_bf};

    const unsigned short* gsrc = gpk  + (size_t)b * NN * 32;
    const unsigned short* vsrc = vblk + (size_t)b * (NN/32) * 1024;
    int mbase = wave * MCHUNK;
    int mb0   = wave * NBLK;

    bf16x8 akc[2], vbc[2];
    {
        int m0 = mbase;
        akc[0] = *(const bf16x8*)(gsrc + (size_t)(m0 + c15)      * 32 + g4*8);
        akc[1] = *(const bf16x8*)(gsrc + (size_t)(m0 + 16 + c15) * 32 + g4*8);
        const unsigned short* vb = vsrc + (size_t)mb0 * 1024 + c15*32 + g4*8;
        vbc[0] = *(const bf16x8*)(vb);
        vbc[1] = *(const bf16x8*)(vb + 512);
    }

    #pragma unroll 2
    for (int t = 0; t < NBLK; t++) {
        bf16x8 akn[2], vbn[2];
        if (t + 1 < NBLK) {
            int m1 = mbase + (t + 1) * MBLK;
            akn[0] = *(const bf16x8*)(gsrc + (size_t)(m1 + c15)      * 32 + g4*8);
            akn[1] = *(const bf16x8*)(gsrc + (size_t)(m1 + 16 + c15) * 32 + g4*8);
            const unsigned short* vb = vsrc + (size_t)(mb0 + t + 1) * 1024
                                     + c15*32 + g4*8;
            vbn[0] = *(const bf16x8*)(vb);
            vbn[1] = *(const bf16x8*)(vb + 512);
        }

        // swapped QK^T: D[m-row][q-col]; exact hi/lo product
        f32x4 sf[2][2];
        #pragma unroll
        for (int mg = 0; mg < 2; mg++)
            #pragma unroll
            for (int qg = 0; qg < 2; qg++)
                sf[qg][mg] = __builtin_amdgcn_mfma_f32_16x16x32_bf16(
                    akc[mg], bq[qg], zero4, 0, 0, 0);

        // exp2 (log2e pre-folded), pack into PV A-fragment (k=r+4*mg+8*g4)
        bf16x8 pa[2];
        #pragma unroll
        for (int qg = 0; qg < 2; qg++) {
            float e00 = ex2(sf[qg][0][0]), e01 = ex2(sf[qg][0][1]);
            float e02 = ex2(sf[qg][0][2]), e03 = ex2(sf[qg][0][3]);
            float e10 = ex2(sf[qg][1][0]), e11 = ex2(sf[qg][1][1]);
            float e12 = ex2(sf[qg][1][2]), e13 = ex2(sf[qg][1][3]);
            union { unsigned int u[4]; bf16x8 v; } pp;
            pp.u[0] = pk2(e00, e01); pp.u[1] = pk2(e02, e03);
            pp.u[2] = pk2(e10, e11); pp.u[3] = pk2(e12, e13);
            pa[qg] = pp.v;
        }

        // P * V (+ L via ones-column on the matrix pipe)
        #pragma unroll
        for (int qg = 0; qg < 2; qg++) {
            #pragma unroll
            for (int hg = 0; hg < 2; hg++)
                acc[qg][hg] = __builtin_amdgcn_mfma_f32_16x16x32_bf16(
                    pa[qg], vbc[hg], acc[qg][hg], 0, 0, 0);
            accL[qg] = __builtin_amdgcn_mfma_f32_16x16x32_bf16(
                    pa[qg], vones, accL[qg], 0, 0, 0);
        }

        if (t + 1 < NBLK) {
            akc[0] = akn[0]; akc[1] = akn[1];
            vbc[0] = vbn[0]; vbc[1] = vbn[1];
        }
    }

    // ---- deterministic wave combine (no atomics) ----
    #pragma unroll
    for (int qg = 0; qg < 2; qg++)
        #pragma unroll
        for (int hg = 0; hg < 2; hg++)
            #pragma unroll
            for (int r = 0; r < 4; r++)
                sl[wave][qg*16 + g4*4 + r][hg*16 + c15] = acc[qg][hg][r];
    // L: every c15 lane holds the same row-sum; c15==0 writes it
    if (c15 == 0) {
        #pragma unroll
        for (int qg = 0; qg < 2; qg++)
            #pragma unroll
            for (int r = 0; r < 4; r++)
                sl[wave][qg*16 + g4*4 + r][HF] = accL[qg][r];
    }
    __syncthreads();

    {
        int q = tid & 31;
        for (int col = tid >> 5; col < HF + 1; col += 16) {
            float s = sl[0][q][col];
            #pragma unroll
            for (int w2 = 1; w2 < WAVES; w2++) s += sl[w2][q][col];
            sl[0][q][col] = s;
        }
    }
    __syncthreads();

    // epilogue: normalize, Wv projection, gamma, residual
    int q  = tid & 31;
    int cb = tid >> 5;
    float rL = 1.f / sl[0][q][HF];
    float o_[HF];
    #pragma unroll
    for (int h = 0; h < HF; h++) o_[h] = sl[0][q][h] * rL;
    float gm = gamma[0];
    size_t obase = (size_t)b * CC * NN + n0 + q;
    for (int c = cb*4; c < cb*4 + 4; c++) {
        float v = bv[c];
        #pragma unroll
        for (int h = 0; h < HF; h++) v += Wv[c*HF + h] * o_[h];
        size_t a = obase + (size_t)c * NN;
        out[a] = gm * v + x[a];
    }
}

extern "C" void kernel_launch(void* const* d_in, const int* in_sizes, int n_in,
                              void* d_out, int out_size, void* d_ws, size_t ws_size,
                              hipStream_t stream) {
    const float* x     = (const float*)d_in[0];
    const float* Wf    = (const float*)d_in[1];
    const float* bf    = (const float*)d_in[2];
    const float* Wg    = (const float*)d_in[3];
    const float* bg    = (const float*)d_in[4];
    const float* Wh    = (const float*)d_in[5];
    const float* bh    = (const float*)d_in[6];
    const float* Wv    = (const float*)d_in[7];
    const float* bv    = (const float*)d_in[8];
    const float* gamma = (const float*)d_in[9];
    float* out = (float*)d_out;

    unsigned short* ws   = (unsigned short*)d_ws;
    unsigned short* fpk  = ws;                               // B*N*16  u16
    unsigned short* gpk  = ws + (size_t)BB*NN*16;            // B*N*32  u16
    unsigned short* vblk = ws + (size_t)BB*NN*48;            // B*128*1024 u16
    // total 2.62 MB

    proj_kernel<<<(BB*NN/128)*6, 128, 0, stream>>>(x, Wf, bf, Wg, bg, Wh, bh,
                                                   fpk, gpk, vblk);
    attn_kernel<<<BB*(NN/QBLK), THREADS, 0, stream>>>(fpk, gpk, vblk,
                                                      Wv, bv, gamma, x, out);
}